// Round 2
// baseline (64.998 us; speedup 1.0000x reference)
//
#include <hip/hip_runtime.h>

// Overlap-add: y[b, f*256 + c] += x[b, c, f]
// x: [16, 1024, 2048] f32, y: [16, 525056] f32
// WIN/HOP = 4 -> y[b, g*256 + r] = sum_{k=0}^{3} x[b, k*256 + r, g - k]  (valid g-k)

constexpr int BATCH   = 16;
constexpr int WIN     = 1024;
constexpr int HOP     = 256;
constexpr int NF      = 2048;                      // frames
constexpr int OUT_LEN = (NF - 1) * HOP + WIN;      // 525056
constexpr int GTOT    = OUT_LEN / HOP;             // 2051
constexpr int FT      = 16;                        // g-values per block tile
constexpr int NTILES  = (GTOT + FT - 1) / FT;      // 129
constexpr int RHALF   = 128;                       // r-range per block
constexpr int RS      = 132;                       // LDS row stride (floats); 132*4=528B, 16B-aligned

// alignment-4 float4 for the shifted (possibly 4B-misaligned) global loads
typedef float f4u __attribute__((ext_vector_type(4), aligned(4)));
// 16B-aligned float4 for LDS reads / global stores
typedef float f4a __attribute__((ext_vector_type(4), aligned(16)));

__global__ __launch_bounds__(256, 8)
void oadd_kernel(const float* __restrict__ x, float* __restrict__ y) {
    // transposed accumulator tile: accT[j][r_local]
    __shared__ __align__(16) float accT[FT][RS];   // 8448 B

    const int tid   = threadIdx.x;
    const int tile  = blockIdx.x;
    const int rhalf = blockIdx.y;
    const int b     = blockIdx.z;
    const int g0    = tile * FT;
    const int rbase = rhalf * RHALF;

    const int q  = tid & 3;    // j-chunk: j = 4q .. 4q+3
    const int rr = tid >> 2;   // 0..63

    const float* __restrict__ xb = x + (size_t)b * WIN * NF;

    // interior iff every f = g0 + j - k (j in [0,FT), k in [0,4)) is in [0, NF)
    const bool interior = (g0 >= 3) && (g0 + FT - 1 <= NF - 1);

    if (interior) {
        #pragma unroll
        for (int ri = 0; ri < 2; ++ri) {
            const int rl = ri * 64 + rr;           // 0..127
            const int r  = rbase + rl;
            const int f0 = g0 + q * 4;
            // 4 independent loads, summed after (no per-load wait chain)
            f4u v0 = *reinterpret_cast<const f4u*>(xb + (size_t)(0 * HOP + r) * NF + (f0 - 0));
            f4u v1 = *reinterpret_cast<const f4u*>(xb + (size_t)(1 * HOP + r) * NF + (f0 - 1));
            f4u v2 = *reinterpret_cast<const f4u*>(xb + (size_t)(2 * HOP + r) * NF + (f0 - 2));
            f4u v3 = *reinterpret_cast<const f4u*>(xb + (size_t)(3 * HOP + r) * NF + (f0 - 3));
            f4u s = (v0 + v1) + (v2 + v3);
            accT[q * 4 + 0][rl] = s.x;
            accT[q * 4 + 1][rl] = s.y;
            accT[q * 4 + 2][rl] = s.z;
            accT[q * 4 + 3][rl] = s.w;
        }
    } else {
        // boundary tiles (first and last): per-element guarded scalar loads
        for (int ri = 0; ri < 2; ++ri) {
            const int rl = ri * 64 + rr;
            const int r  = rbase + rl;
            float a[4] = {0.f, 0.f, 0.f, 0.f};
            for (int k = 0; k < 4; ++k) {
                const size_t crow = (size_t)(k * HOP + r) * NF;
                #pragma unroll
                for (int m = 0; m < 4; ++m) {
                    const int f = g0 + q * 4 + m - k;
                    if (f >= 0 && f < NF) a[m] += xb[crow + f];
                }
            }
            #pragma unroll
            for (int m = 0; m < 4; ++m) accT[q * 4 + m][rl] = a[m];
        }
    }

    __syncthreads();

    // vectorized coalesced write-out: half-wave per j-row, float4 per lane
    float* __restrict__ yb = y + (size_t)b * OUT_LEN;
    const int c4 = (tid & 31) * 4;                 // 0..124
    #pragma unroll
    for (int it = 0; it < 2; ++it) {
        const int j = it * 8 + (tid >> 5);         // 0..15
        const int g = g0 + j;
        if (g < GTOT) {
            f4a v = *reinterpret_cast<const f4a*>(&accT[j][c4]);
            *reinterpret_cast<f4a*>(&yb[(size_t)g * HOP + rbase + c4]) = v;
        }
    }
}

extern "C" void kernel_launch(void* const* d_in, const int* in_sizes, int n_in,
                              void* d_out, int out_size, void* d_ws, size_t ws_size,
                              hipStream_t stream) {
    const float* x = (const float*)d_in[0];
    float* y = (float*)d_out;
    dim3 grid(NTILES, 2, BATCH);
    oadd_kernel<<<grid, 256, 0, stream>>>(x, y);
}

// Round 3
// 51.592 us; speedup vs baseline: 1.2599x; 1.2599x over previous
//
#include <hip/hip_runtime.h>

// Overlap-add: y[b, f*256 + c] += x[b, c, f]
// x: [16, 1024, 2048] f32, y: [16, 525056] f32
// WIN/HOP = 4 -> y[b, g*256 + r] = sum_{k=0}^{3} x[b, k*256 + r, g - k]  (valid g-k)
//
// Key idea this round: one wave = one full x-row window. All 64 lanes read
// 256 consecutive f of a single row -> each load instruction is ONE
// contiguous 1 KB segment (DRAM-page friendly), instead of 8-16 scattered
// 64-128B segments at 8KB stride.

constexpr int BATCH   = 16;
constexpr int WIN     = 1024;
constexpr int HOP     = 256;
constexpr int NF      = 2048;                      // frames
constexpr int OUT_LEN = (NF - 1) * HOP + WIN;      // 525056
constexpr int GTOT    = OUT_LEN / HOP;             // 2051
constexpr int FT      = 256;                       // g-values per tile
constexpr int NTILES  = (GTOT + FT - 1) / FT;      // 9 (tile 8 = 3 g's, slow path)
constexpr int RB      = 32;                        // r-values per block
constexpr int NRS     = HOP / RB;                  // 8
constexpr int RS2     = FT + 4;                    // 260 floats = 1040 B row stride (16B-aligned, bank-rotating)

// alignment-4 float4: the per-k shift (-k floats) misaligns 16B vectors
typedef float f4u __attribute__((ext_vector_type(4), aligned(4)));
// 16B-aligned float4 for LDS vector writes / global stores
typedef float f4a __attribute__((ext_vector_type(4), aligned(16)));

__global__ __launch_bounds__(256, 4)
void oadd_kernel(const float* __restrict__ x, float* __restrict__ y) {
    // accT2[rl][j]: tile transposed; phase-1 writes are dense 16B rows
    __shared__ __align__(16) float accT2[RB][RS2];   // 33280 B -> 4 blocks/CU

    const int tid   = threadIdx.x;
    const int tile  = blockIdx.x;
    const int rsp   = blockIdx.y;
    const int b     = blockIdx.z;
    const int g0    = tile * FT;
    const int rbase = rsp * RB;

    const int q = tid & 63;    // lane: j-chunk [4q, 4q+4); whole wave = j 0..255 contiguous
    const int w = tid >> 6;    // wave id 0..3

    const float* __restrict__ xb = x + (size_t)b * WIN * NF;

    // interior iff every f = g0 + 4q + m - k in [0, NF): g0 >= 3 and g0+255 <= 2047
    const bool interior = (g0 >= 3) && (g0 + FT - 1 <= NF - 1);

    if (interior) {
        #pragma unroll
        for (int ri = 0; ri < 8; ++ri) {
            const int rl = ri * 4 + w;             // wave-uniform row
            const int r  = rbase + rl;
            const float* base = xb + (size_t)r * NF + (g0 + q * 4);
            // 4 independent 1KB-wave-contiguous loads (rows k*256+r, window shifted by -k)
            f4u v0 = *reinterpret_cast<const f4u*>(base + (size_t)(0 * HOP) * NF - 0);
            f4u v1 = *reinterpret_cast<const f4u*>(base + (size_t)(1 * HOP) * NF - 1);
            f4u v2 = *reinterpret_cast<const f4u*>(base + (size_t)(2 * HOP) * NF - 2);
            f4u v3 = *reinterpret_cast<const f4u*>(base + (size_t)(3 * HOP) * NF - 3);
            f4u s = (v0 + v1) + (v2 + v3);
            *reinterpret_cast<f4a*>(&accT2[rl][q * 4]) = s;   // dense row write
        }
    } else {
        // boundary tiles (0 and 8): per-element guarded scalar loads
        for (int ri = 0; ri < 8; ++ri) {
            const int rl = ri * 4 + w;
            const int r  = rbase + rl;
            float a[4] = {0.f, 0.f, 0.f, 0.f};
            for (int k = 0; k < 4; ++k) {
                const size_t crow = (size_t)(k * HOP + r) * NF;
                #pragma unroll
                for (int m = 0; m < 4; ++m) {
                    const int f = g0 + q * 4 + m - k;
                    if (f >= 0 && f < NF) a[m] += xb[crow + f];
                }
            }
            #pragma unroll
            for (int m = 0; m < 4; ++m) accT2[rl][q * 4 + m] = a[m];
        }
    }

    __syncthreads();

    // write-out: thread gathers 4 consecutive rl for one j -> coalesced f4 store
    float* __restrict__ yb = y + (size_t)b * OUT_LEN;
    const int c4 = (tid & 7) * 4;     // 0..28
    const int jj = tid >> 3;          // 0..31
    #pragma unroll
    for (int pass = 0; pass < 8; ++pass) {
        const int j = pass * 32 + jj;
        const int g = g0 + j;
        if (g < GTOT) {
            f4a v;
            v.x = accT2[c4 + 0][j];
            v.y = accT2[c4 + 1][j];
            v.z = accT2[c4 + 2][j];
            v.w = accT2[c4 + 3][j];
            *reinterpret_cast<f4a*>(&yb[(size_t)g * HOP + rbase + c4]) = v;
        }
    }
}

extern "C" void kernel_launch(void* const* d_in, const int* in_sizes, int n_in,
                              void* d_out, int out_size, void* d_ws, size_t ws_size,
                              hipStream_t stream) {
    const float* x = (const float*)d_in[0];
    float* y = (float*)d_out;
    dim3 grid(NTILES, NRS, BATCH);
    oadd_kernel<<<grid, 256, 0, stream>>>(x, y);
}

// Round 4
// 41.880 us; speedup vs baseline: 1.5520x; 1.2319x over previous
//
#include <hip/hip_runtime.h>

// Overlap-add: y[b, f*256 + c] += x[b, c, f]
// x: [16, 1024, 2048] f32, y: [16, 525056] f32
// WIN/HOP = 4 -> y[b, g*256 + r] = sum_{k=0}^{3} x[b, k*256 + r, g - k]  (valid g-k)
//
// R4: 2176 blocks (8/CU resident, full 32-wave occupancy), 16 independent
// loads per thread issued in batches of 8 before any consumer, per-lane
// boundary guards (no scalar slow-path blocks).

constexpr int BATCH   = 16;
constexpr int WIN     = 1024;
constexpr int HOP     = 256;
constexpr int NF      = 2048;                      // frames
constexpr int OUT_LEN = (NF - 1) * HOP + WIN;      // 525056
constexpr int GTOT    = OUT_LEN / HOP;             // 2051
constexpr int FT      = 128;                       // g-values per tile
constexpr int NTILES  = (GTOT + FT - 1) / FT;      // 17
constexpr int RB      = 32;                        // r-values per block
constexpr int NRS     = HOP / RB;                  // 8
constexpr int RS2     = FT + 4;                    // 132 floats (528B, 16B-aligned rows)

// alignment-4 float4: the per-k shift (-k floats) misaligns 16B vectors
typedef float f4u __attribute__((ext_vector_type(4), aligned(4)));
// 16B-aligned float4 for LDS accesses / global stores
typedef float f4a __attribute__((ext_vector_type(4), aligned(16)));

__global__ __launch_bounds__(256, 8)
void oadd_kernel(const float* __restrict__ x, float* __restrict__ y) {
    // accT2[rl][j]: transposed accumulator tile
    __shared__ __align__(16) float accT2[RB][RS2];   // 16896 B -> 8 blocks/CU

    const int tid   = threadIdx.x;
    const int tile  = blockIdx.x;
    const int rsp   = blockIdx.y;
    const int b     = blockIdx.z;
    const int g0    = tile * FT;
    const int rbase = rsp * RB;

    const int lane = tid & 63;
    const int w    = tid >> 6;            // wave 0..3
    const int fq   = (lane & 31) * 4;     // f-chunk within tile: 0..124
    const int rh   = lane >> 5;           // row half: 0/1 (wave = 2 rows x 512B)

    const float* __restrict__ xb = x + (size_t)b * WIN * NF;

    // interior iff all f = g0 + j - k (j in [0,FT), k in [0,4)) are in [0,NF)
    const bool interior = (g0 >= 3) && (g0 + FT - 1 <= NF - 1);

    if (interior) {
        #pragma unroll
        for (int ip = 0; ip < 2; ++ip) {
            // batch: 8 fully-independent loads (2 row-groups x 4 shifts)
            f4u v[2][4];
            #pragma unroll
            for (int i2 = 0; i2 < 2; ++i2) {
                const int it = ip * 2 + i2;
                const int rl = it * 8 + w * 2 + rh;
                const float* rp = xb + (size_t)(rbase + rl) * NF + (g0 + fq);
                #pragma unroll
                for (int k = 0; k < 4; ++k) {
                    v[i2][k] = *reinterpret_cast<const f4u*>(rp + (size_t)(k * HOP) * NF - k);
                }
            }
            #pragma unroll
            for (int i2 = 0; i2 < 2; ++i2) {
                const int it = ip * 2 + i2;
                const int rl = it * 8 + w * 2 + rh;
                f4u s = (v[i2][0] + v[i2][1]) + (v[i2][2] + v[i2][3]);
                *reinterpret_cast<f4a*>(&accT2[rl][fq]) = s;
            }
        }
    } else {
        // boundary tiles (0 and 16): per-lane guards, vector load when safe
        #pragma unroll
        for (int it = 0; it < 4; ++it) {
            const int rl = it * 8 + w * 2 + rh;
            const int r  = rbase + rl;
            float a[4] = {0.f, 0.f, 0.f, 0.f};
            #pragma unroll
            for (int k = 0; k < 4; ++k) {
                const float* rp = xb + (size_t)(k * HOP + r) * NF;
                const int f0 = g0 + fq - k;
                if (f0 >= 0 && f0 + 3 <= NF - 1) {
                    f4u vv = *reinterpret_cast<const f4u*>(rp + f0);
                    a[0] += vv.x; a[1] += vv.y; a[2] += vv.z; a[3] += vv.w;
                } else {
                    #pragma unroll
                    for (int m = 0; m < 4; ++m) {
                        const int f = f0 + m;
                        if (f >= 0 && f < NF) a[m] += rp[f];
                    }
                }
            }
            accT2[rl][fq + 0] = a[0];
            accT2[rl][fq + 1] = a[1];
            accT2[rl][fq + 2] = a[2];
            accT2[rl][fq + 3] = a[3];
        }
    }

    __syncthreads();

    // write-out: thread gathers 4 consecutive rl for one j -> 128B-coalesced f4 stores
    float* __restrict__ yb = y + (size_t)b * OUT_LEN;
    const int c4 = (tid & 7) * 4;     // 0..28
    const int jj = tid >> 3;          // 0..31
    #pragma unroll
    for (int pass = 0; pass < 4; ++pass) {
        const int j = pass * 32 + jj;
        const int g = g0 + j;
        if (g < GTOT) {
            f4a v;
            v.x = accT2[c4 + 0][j];
            v.y = accT2[c4 + 1][j];
            v.z = accT2[c4 + 2][j];
            v.w = accT2[c4 + 3][j];
            *reinterpret_cast<f4a*>(&yb[(size_t)g * HOP + rbase + c4]) = v;
        }
    }
}

extern "C" void kernel_launch(void* const* d_in, const int* in_sizes, int n_in,
                              void* d_out, int out_size, void* d_ws, size_t ws_size,
                              hipStream_t stream) {
    const float* x = (const float*)d_in[0];
    float* y = (float*)d_out;
    dim3 grid(NTILES, NRS, BATCH);
    oadd_kernel<<<grid, 256, 0, stream>>>(x, y);
}